// Round 6
// baseline (270.783 us; speedup 1.0000x reference)
//
#include <hip/hip_runtime.h>
#include <hip/hip_bf16.h>
#include <math.h>

#define LORA_SCALE 8.0f

typedef __attribute__((ext_vector_type(8))) short bf16x8;
typedef __attribute__((ext_vector_type(4))) float f32x4;
typedef unsigned short u16;
typedef unsigned int u32;

__device__ __forceinline__ u16 f2bf(float f) {
    u32 u = __float_as_uint(f);
    u += 0x7FFFu + ((u >> 16) & 1u);      // RNE to bf16
    return (u16)(u >> 16);
}
__device__ __forceinline__ float bf2f(u16 s) {
    return __uint_as_float(((u32)s) << 16);
}
__device__ __forceinline__ u32 pack2(float lo, float hi) {
    return (u32)f2bf(lo) | ((u32)f2bf(hi) << 16);
}
__device__ __forceinline__ void split2(float a, float b, u32& hw, u32& lw) {
    u16 ha = f2bf(a), hb = f2bf(b);
    float ra = a - bf2f(ha), rb = b - bf2f(hb);
    hw = (u32)ha | ((u32)hb << 16);
    lw = (u32)f2bf(ra) | ((u32)f2bf(rb) << 16);
}
__device__ __forceinline__ void g2lds16(const void* g, void* l) {
    __builtin_amdgcn_global_load_lds(
        (const __attribute__((address_space(1))) void*)g,
        (__attribute__((address_space(3))) void*)l, 16, 0, 0);
}

union Frag { bf16x8 v; u32 u[4]; };

// ---------------- pre-pass: split f32 -> bf16 hi/lo (8 elems/thread) ----------------
__global__ __launch_bounds__(256) void split_kernel(
    const float* __restrict__ in, u16* __restrict__ hi, u16* __restrict__ lo, int n8)
{
    int i = blockIdx.x * 256 + threadIdx.x;
    if (i >= n8) return;
    const float* p = in + (size_t)i * 8;
    u32 hw[4], lw[4];
#pragma unroll
    for (int j = 0; j < 4; ++j) split2(p[2 * j], p[2 * j + 1], hw[j], lw[j]);
    *(uint4*)&hi[(size_t)i * 8] = make_uint4(hw[0], hw[1], hw[2], hw[3]);
    *(uint4*)&lo[(size_t)i * 8] = make_uint4(lw[0], lw[1], lw[2], lw[3]);
}

// ---------------- pre-pass: transpose + split  W[Kd][Nd] f32 -> T{h,l}[Nd][Kd] bf16 ----
__global__ __launch_bounds__(256) void transconv_kernel(
    const float* __restrict__ W, u16* __restrict__ Th, u16* __restrict__ Tl,
    int Kd, int Nd)
{
    __shared__ float t[32][36];
    const int r0 = blockIdx.y * 32;
    const int c0 = blockIdx.x * 32;
    const int tid = threadIdx.x;
    {
        int r = tid >> 3, c4 = (tid & 7) * 4;
        float4 v = *(const float4*)&W[(size_t)(r0 + r) * Nd + c0 + c4];
        t[r][c4 + 0] = v.x; t[r][c4 + 1] = v.y; t[r][c4 + 2] = v.z; t[r][c4 + 3] = v.w;
    }
    __syncthreads();
    int oc = tid >> 3;
    int oi = tid & 7;
    u32 hw[2], lw[2];
    split2(t[4 * oi + 0][oc], t[4 * oi + 1][oc], hw[0], lw[0]);
    split2(t[4 * oi + 2][oc], t[4 * oi + 3][oc], hw[1], lw[1]);
    size_t o = (size_t)(c0 + oc) * Kd + r0 + 4 * oi;
    *(uint2*)&Th[o] = make_uint2(hw[0], hw[1]);
    *(uint2*)&Tl[o] = make_uint2(lw[0], lw[1]);
}

// ---------------- K1: lora down-projection  xa[M,4] = X[M,K] @ A[K,4] ----------------
__global__ __launch_bounds__(64) void lora_down_kernel(
    const float* __restrict__ X, const float* __restrict__ A,
    float* __restrict__ out, int K)
{
    const int row = blockIdx.x;
    const int lane = threadIdx.x;
    const float* xr = X + (size_t)row * K;
    float a0 = 0.f, a1 = 0.f, a2 = 0.f, a3 = 0.f;
    for (int c4 = lane * 4; c4 < K; c4 += 256) {
        float4 xv = *(const float4*)&xr[c4];
        const float* ap = &A[(size_t)c4 * 4];
        float4 A0 = *(const float4*)&ap[0];
        float4 A1 = *(const float4*)&ap[4];
        float4 A2 = *(const float4*)&ap[8];
        float4 A3 = *(const float4*)&ap[12];
        a0 = fmaf(xv.x, A0.x, a0); a1 = fmaf(xv.x, A0.y, a1);
        a2 = fmaf(xv.x, A0.z, a2); a3 = fmaf(xv.x, A0.w, a3);
        a0 = fmaf(xv.y, A1.x, a0); a1 = fmaf(xv.y, A1.y, a1);
        a2 = fmaf(xv.y, A1.z, a2); a3 = fmaf(xv.y, A1.w, a3);
        a0 = fmaf(xv.z, A2.x, a0); a1 = fmaf(xv.z, A2.y, a1);
        a2 = fmaf(xv.z, A2.z, a2); a3 = fmaf(xv.z, A2.w, a3);
        a0 = fmaf(xv.w, A3.x, a0); a1 = fmaf(xv.w, A3.y, a1);
        a2 = fmaf(xv.w, A3.z, a2); a3 = fmaf(xv.w, A3.w, a3);
    }
#pragma unroll
    for (int off = 32; off > 0; off >>= 1) {
        a0 += __shfl_down(a0, off);
        a1 += __shfl_down(a1, off);
        a2 += __shfl_down(a2, off);
        a3 += __shfl_down(a3, off);
    }
    if (lane == 0) {
        float4 r; r.x = a0; r.y = a1; r.z = a2; r.w = a3;
        *(float4*)&out[(size_t)row * 4] = r;
    }
}

// ---------------- split-bf16 MFMA GEMM, counted-vmcnt ring pipeline (T3+T4+T5) --------
// C[M,N] = (Ah+Al)[M,K] @ (Bh+Bl)^T[N,K]; 128x128 tile, BK=32, 8 waves (4x2 grid of
// 32x64 sub-tiles). bf16x3 via SWAPPED mfma(B,A) -> vector stores. Every thread stages
// one 16B chunk of each of the 4 arrays per K-step (global_load_lds, linear LDS dest =
// tid*16; chunk-XOR swizzle on the GLOBAL source, same XOR on frag reads).
// Ring: stage t0,t1; per step: vmcnt(4) [t+1 stays in flight] -> barrier -> ds_read ->
// lgkmcnt(0) -> barrier -> stage t+2 into freed buffer -> setprio(1) MFMA setprio(0).
// Grid 1-D, XCD-chunked decode (T1).
template<bool OUTBF, bool LORA, bool BIAS>
__global__ __launch_bounds__(512, 4) void gemm_split_kernel(
    const u16* __restrict__ Ah, const u16* __restrict__ Al,
    const u16* __restrict__ Bh, const u16* __restrict__ Bl,
    void* __restrict__ Cout, int M, int N, int K,
    const float* __restrict__ XA, const float* __restrict__ LB,
    const float* __restrict__ bias)
{
    __shared__ __align__(16) u16 Ls[2][4][4096];   // [dbuf][Ahi,Alo,Bhi,Blo][128*32]
    const int tid = threadIdx.x;
    const int w = tid >> 6, lane = tid & 63;
    const int lc = lane & 15, lg = lane >> 4;
    const int wr = w >> 1, wc = w & 1;            // wave sub-tile: rows wr*32, cols wc*64

    const unsigned nbx = (unsigned)N >> 7;
    const unsigned cpx = gridDim.x >> 3;
    const unsigned bid = blockIdx.x;
    const unsigned lid = (bid & 7) * cpx + (bid >> 3);
    const int m0 = (int)(lid / nbx) * 128;
    const int n0 = (int)(lid % nbx) * 128;

    // staging addresses: thread covers row sr = tid>>2, slot = tid&3 of every array;
    // LDS dest = array base + tid*16 B (linear, DMA-compatible); source k-chunk is
    // inverse-swizzled: cg = slot ^ ((sr>>1)&3).
    const int sr = tid >> 2;
    const int scg = ((tid & 3) ^ ((sr >> 1) & 3)) * 8;
    const u16* sAh = Ah + (size_t)(m0 + sr) * K + scg;
    const u16* sAl = Al + (size_t)(m0 + sr) * K + scg;
    const u16* sBh = Bh + (size_t)(n0 + sr) * K + scg;
    const u16* sBl = Bl + (size_t)(n0 + sr) * K + scg;

#define STAGE(buf, kt) do { const int _k0 = (kt) << 5;                      \
        g2lds16(sAh + _k0, (u16*)Ls[buf][0] + tid * 8);                     \
        g2lds16(sAl + _k0, (u16*)Ls[buf][1] + tid * 8);                     \
        g2lds16(sBh + _k0, (u16*)Ls[buf][2] + tid * 8);                     \
        g2lds16(sBl + _k0, (u16*)Ls[buf][3] + tid * 8); } while (0)

    f32x4 acc[2][4];
#pragma unroll
    for (int i = 0; i < 2; ++i)
#pragma unroll
        for (int j = 0; j < 4; ++j) acc[i][j] = (f32x4){0.f, 0.f, 0.f, 0.f};

    const int aswz = (lg ^ ((lc >> 1) & 3)) * 8;
    const int aoff = (wr * 32 + lc) * 32 + aswz;      // + i*512 for m-frag i
    const int boff = (wc * 64 + lc) * 32 + aswz;      // + j*512 for n-frag j

    const int nt = K >> 5;
    STAGE(0, 0);
    STAGE(1, 1);

    for (int t = 0; t < nt; ++t) {
        const int cur = t & 1;
        if (t + 1 < nt) { asm volatile("s_waitcnt vmcnt(4)" ::: "memory"); }
        else            { asm volatile("s_waitcnt vmcnt(0)" ::: "memory"); }
        __builtin_amdgcn_sched_barrier(0);
        __builtin_amdgcn_s_barrier();          // buf[cur] staged by all waves
        __builtin_amdgcn_sched_barrier(0);

        const u16* cb = &Ls[cur][0][0];
        bf16x8 af[2][2], bfr[4][2];
#pragma unroll
        for (int i = 0; i < 2; ++i) {
            af[i][0] = *(const bf16x8*)&cb[aoff + i * 512];
            af[i][1] = *(const bf16x8*)&cb[4096 + aoff + i * 512];
        }
#pragma unroll
        for (int j = 0; j < 4; ++j) {
            bfr[j][0] = *(const bf16x8*)&cb[8192 + boff + j * 512];
            bfr[j][1] = *(const bf16x8*)&cb[12288 + boff + j * 512];
        }
        asm volatile("s_waitcnt lgkmcnt(0)" ::: "memory");
        __builtin_amdgcn_sched_barrier(0);
        __builtin_amdgcn_s_barrier();          // all waves done reading buf[cur]
        __builtin_amdgcn_sched_barrier(0);

        if (t + 2 < nt) STAGE(cur, t + 2);     // overwrite freed buffer; stays in flight
        __builtin_amdgcn_sched_barrier(0);

        __builtin_amdgcn_s_setprio(1);
#pragma unroll
        for (int i = 0; i < 2; ++i)
#pragma unroll
            for (int j = 0; j < 4; ++j) {
                acc[i][j] = __builtin_amdgcn_mfma_f32_16x16x32_bf16(bfr[j][0], af[i][0], acc[i][j], 0, 0, 0);
                acc[i][j] = __builtin_amdgcn_mfma_f32_16x16x32_bf16(bfr[j][0], af[i][1], acc[i][j], 0, 0, 0);
                acc[i][j] = __builtin_amdgcn_mfma_f32_16x16x32_bf16(bfr[j][1], af[i][0], acc[i][j], 0, 0, 0);
            }
        __builtin_amdgcn_s_setprio(0);
    }
#undef STAGE

    // epilogue: lane holds rows m0+wr*32+i*16+lc, cols n0+wc*64+j*16+lg*4..+3
    float4 xa4[2];
    if (LORA) {
#pragma unroll
        for (int i = 0; i < 2; ++i)
            xa4[i] = *(const float4*)&XA[(size_t)(m0 + wr * 32 + i * 16 + lc) * 4];
    }
#pragma unroll
    for (int j = 0; j < 4; ++j) {
        const int col = n0 + wc * 64 + j * 16 + lg * 4;
        float4 lb0, lb1, lb2, lb3, bb;
        if (LORA) {
            lb0 = *(const float4*)&LB[0 * N + col];
            lb1 = *(const float4*)&LB[1 * N + col];
            lb2 = *(const float4*)&LB[2 * N + col];
            lb3 = *(const float4*)&LB[3 * N + col];
        }
        if (BIAS) bb = *(const float4*)&bias[col];
#pragma unroll
        for (int i = 0; i < 2; ++i) {
            const int row = m0 + wr * 32 + i * 16 + lc;
            float v0 = acc[i][j][0], v1 = acc[i][j][1], v2 = acc[i][j][2], v3 = acc[i][j][3];
            if (LORA) {
                v0 += LORA_SCALE * (xa4[i].x * lb0.x + xa4[i].y * lb1.x + xa4[i].z * lb2.x + xa4[i].w * lb3.x);
                v1 += LORA_SCALE * (xa4[i].x * lb0.y + xa4[i].y * lb1.y + xa4[i].z * lb2.y + xa4[i].w * lb3.y);
                v2 += LORA_SCALE * (xa4[i].x * lb0.z + xa4[i].y * lb1.z + xa4[i].z * lb2.z + xa4[i].w * lb3.z);
                v3 += LORA_SCALE * (xa4[i].x * lb0.w + xa4[i].y * lb1.w + xa4[i].z * lb2.w + xa4[i].w * lb3.w);
            }
            if (BIAS) { v0 += bb.x; v1 += bb.y; v2 += bb.z; v3 += bb.w; }
            if (OUTBF) {
                uint2 o2; o2.x = pack2(v0, v1); o2.y = pack2(v2, v3);
                *(uint2*)&((u16*)Cout)[(size_t)row * N + col] = o2;
            } else {
                *(float4*)&((float*)Cout)[(size_t)row * N + col] = make_float4(v0, v1, v2, v3);
            }
        }
    }
}

// ---------------- K3: MFMA bf16 flash attention (T14 staging + T5 setprio) ------------
__global__ __launch_bounds__(256, 3) void flash_mfma_kernel(
    const u16* __restrict__ qkv, u16* __restrict__ aoh, u16* __restrict__ aol)
{
    __shared__ __align__(16) short Kl[32][72];
    __shared__ __align__(16) short Vl[64][40];
    const int fid = blockIdx.x;
    const int bh = fid % 96;
    const int qx = fid / 96;
    const int b = bh / 12, h = bh - b * 12;
    const int tid = threadIdx.x;
    const int w = tid >> 6, lane = tid & 63;
    const int lc = lane & 15, lg = lane >> 4;
    const u16* base = qkv + (size_t)b * 1024 * 2304;
    const int q0 = qx * 128 + w * 32;

    Frag qf[2][2];
#pragma unroll
    for (int qi = 0; qi < 2; ++qi)
#pragma unroll
        for (int dc = 0; dc < 2; ++dc)
            qf[qi][dc].v = *(const bf16x8*)&base[(size_t)(q0 + qi * 16 + lc) * 2304 + h * 64 + dc * 32 + lg * 8];

    f32x4 o[2][4];
#pragma unroll
    for (int qi = 0; qi < 2; ++qi)
#pragma unroll
        for (int df = 0; df < 4; ++df) o[qi][df] = (f32x4){0.f, 0.f, 0.f, 0.f};
    float mrow[2] = {-1e30f, -1e30f};
    float lrow[2] = {0.f, 0.f};
    const float SC = 0.125f * 1.44269504f;

    const u16* kvbase = base + 768 + h * 64;
    const int skk = tid >> 4, sd0 = (tid & 15) * 4;
    uint2 pk[2], pv[2];
#pragma unroll
    for (int rep = 0; rep < 2; ++rep) {
        const u16* gp = kvbase + (size_t)(skk + rep * 16) * 2304 + sd0;
        pk[rep] = *(const uint2*)gp;
        pv[rep] = *(const uint2*)(gp + 768);
    }

    for (int kv0 = 0; kv0 < 1024; kv0 += 32) {
        __syncthreads();
#pragma unroll
        for (int rep = 0; rep < 2; ++rep) {
            int kk = skk + rep * 16;
            *(uint2*)&Kl[kk][sd0] = pk[rep];
            Vl[sd0 + 0][kk] = (short)(pv[rep].x & 0xFFFF);
            Vl[sd0 + 1][kk] = (short)(pv[rep].x >> 16);
            Vl[sd0 + 2][kk] = (short)(pv[rep].y & 0xFFFF);
            Vl[sd0 + 3][kk] = (short)(pv[rep].y >> 16);
        }
        if (kv0 + 32 < 1024) {
#pragma unroll
            for (int rep = 0; rep < 2; ++rep) {
                const u16* gp = kvbase + (size_t)(kv0 + 32 + skk + rep * 16) * 2304 + sd0;
                pk[rep] = *(const uint2*)gp;
                pv[rep] = *(const uint2*)(gp + 768);
            }
        }
        __syncthreads();

        bf16x8 kA[2][2], vA[4];
#pragma unroll
        for (int kf = 0; kf < 2; ++kf)
#pragma unroll
            for (int dc = 0; dc < 2; ++dc)
                kA[kf][dc] = *(const bf16x8*)&Kl[kf * 16 + lc][dc * 32 + lg * 8];
#pragma unroll
        for (int df = 0; df < 4; ++df)
            vA[df] = *(const bf16x8*)&Vl[df * 16 + lc][lg * 8];

#pragma unroll
        for (int qi = 0; qi < 2; ++qi) {
            f32x4 s0 = {0.f, 0.f, 0.f, 0.f}, s1 = {0.f, 0.f, 0.f, 0.f};
            __builtin_amdgcn_s_setprio(1);
            s0 = __builtin_amdgcn_mfma_f32_16x16x32_bf16(kA[0][0], qf[qi][0].v, s0, 0, 0, 0);
            s0 = __builtin_amdgcn_mfma_f32_16x16x32_bf16(kA[0][1], qf[qi][1].v, s0, 0, 0, 0);
            s1 = __builtin_amdgcn_mfma_f32_16x16x32_bf16(kA[1][0], qf[qi][0].v, s1, 0, 0, 0);
            s1 = __builtin_amdgcn_mfma_f32_16x16x32_bf16(kA[1][1], qf[qi][1].v, s1, 0, 0, 0);
            __builtin_amdgcn_s_setprio(0);

            float t0[4], t1[4];
#pragma unroll
            for (int r = 0; r < 4; ++r) { t0[r] = s0[r] * SC; t1[r] = s1[r] * SC; }
            float pm = fmaxf(fmaxf(fmaxf(t0[0], t0[1]), fmaxf(t0[2], t0[3])),
                             fmaxf(fmaxf(t1[0], t1[1]), fmaxf(t1[2], t1[3])));
            pm = fmaxf(pm, __shfl_xor(pm, 16, 64));
            pm = fmaxf(pm, __shfl_xor(pm, 32, 64));
            float nm = fmaxf(mrow[qi], pm);
            float corr = exp2f(mrow[qi] - nm);
            mrow[qi] = nm;
            float p0[4], p1[4];
            float rs = 0.f;
#pragma unroll
            for (int r = 0; r < 4; ++r) {
                p0[r] = exp2f(t0[r] - nm); rs += p0[r];
                p1[r] = exp2f(t1[r] - nm); rs += p1[r];
            }
            rs += __shfl_xor(rs, 16, 64);
            rs += __shfl_xor(rs, 32, 64);
            lrow[qi] = lrow[qi] * corr + rs;
#pragma unroll
            for (int df = 0; df < 4; ++df) o[qi][df] *= corr;

            u32 w00 = pack2(p0[0], p0[1]);
            u32 w01 = pack2(p0[2], p0[3]);
            u32 w10 = pack2(p1[0], p1[1]);
            u32 w11 = pack2(p1[2], p1[3]);
            Frag pa;
            const int gsel = (lg & 1) * 2;
#pragma unroll
            for (int c = 0; c < 4; ++c) {
                int src = lc | ((gsel + (c >> 1)) << 4);
                u32 a0 = (u32)__shfl((int)((c & 1) ? w01 : w00), src, 64);
                u32 a1 = (u32)__shfl((int)((c & 1) ? w11 : w10), src, 64);
                pa.u[c] = (lg >> 1) ? a1 : a0;
            }
            __builtin_amdgcn_s_setprio(1);
#pragma unroll
            for (int df = 0; df < 4; ++df)
                o[qi][df] = __builtin_amdgcn_mfma_f32_16x16x32_bf16(vA[df], pa.v, o[qi][df], 0, 0, 0);
            __builtin_amdgcn_s_setprio(0);
        }
    }

#pragma unroll
    for (int qi = 0; qi < 2; ++qi) {
        float inv = 1.f / lrow[qi];
        size_t rowoff = (size_t)(b * 1024 + q0 + qi * 16 + lc) * 768 + h * 64;
#pragma unroll
        for (int df = 0; df < 4; ++df) {
            float v0 = o[qi][df][0] * inv, v1 = o[qi][df][1] * inv;
            float v2 = o[qi][df][2] * inv, v3 = o[qi][df][3] * inv;
            u32 h0, l0, h1, l1;
            split2(v0, v1, h0, l0);
            split2(v2, v3, h1, l1);
            *(uint2*)&aoh[rowoff + df * 16 + lg * 4] = make_uint2(h0, h1);
            *(uint2*)&aol[rowoff + df * 16 + lg * 4] = make_uint2(l0, l1);
        }
    }
}

// ---------------- K5+K6 fused: out += 8 * (out @ A_proj) @ B_proj, one row/block ------
__global__ __launch_bounds__(64) void lora_proj_fused_kernel(
    float* __restrict__ out, const float* __restrict__ A, const float* __restrict__ Bp)
{
    const int row = blockIdx.x;
    const int lane = threadIdx.x;
    float* orow = out + (size_t)row * 768;
    float4 v[3];
    float a0 = 0.f, a1 = 0.f, a2 = 0.f, a3 = 0.f;
#pragma unroll
    for (int s = 0; s < 3; ++s) {
        const int c = s * 256 + lane * 4;
        v[s] = *(const float4*)&orow[c];
        const float* ap = &A[(size_t)c * 4];
        float4 A0 = *(const float4*)&ap[0];
        float4 A1 = *(const float4*)&ap[4];
        float4 A2 = *(const float4*)&ap[8];
        float4 A3 = *(const float4*)&ap[12];
        a0 = fmaf(v[s].x, A0.x, a0); a1 = fmaf(v[s].x, A0.y, a1);
        a2 = fmaf(v[s].x, A0.z, a2); a3 = fmaf(v[s].x, A0.w, a3);
        a0 = fmaf(v[s].y, A1.x, a0); a1 = fmaf(v[s].y, A1.y, a1);
        a2 = fmaf(v[s].y, A1.z, a2); a3 = fmaf(v[s].y, A1.w, a3);
        a0 = fmaf(v[s].z, A2.x, a0); a1 = fmaf(v[s].z, A2.y, a1);
        a2 = fmaf(v[s].z, A2.z, a2); a3 = fmaf(v[s].z, A2.w, a3);
        a0 = fmaf(v[s].w, A3.x, a0); a1 = fmaf(v[s].w, A3.y, a1);
        a2 = fmaf(v[s].w, A3.z, a2); a3 = fmaf(v[s].w, A3.w, a3);
    }
#pragma unroll
    for (int off = 1; off < 64; off <<= 1) {
        a0 += __shfl_xor(a0, off);
        a1 += __shfl_xor(a1, off);
        a2 += __shfl_xor(a2, off);
        a3 += __shfl_xor(a3, off);
    }
    a0 *= LORA_SCALE; a1 *= LORA_SCALE; a2 *= LORA_SCALE; a3 *= LORA_SCALE;
#pragma unroll
    for (int s = 0; s < 3; ++s) {
        const int c = s * 256 + lane * 4;
        float4 b0 = *(const float4*)&Bp[0 * 768 + c];
        float4 b1 = *(const float4*)&Bp[1 * 768 + c];
        float4 b2 = *(const float4*)&Bp[2 * 768 + c];
        float4 b3 = *(const float4*)&Bp[3 * 768 + c];
        float4 r = v[s];
        r.x += a0 * b0.x + a1 * b1.x + a2 * b2.x + a3 * b3.x;
        r.y += a0 * b0.y + a1 * b1.y + a2 * b2.y + a3 * b3.y;
        r.z += a0 * b0.z + a1 * b1.z + a2 * b2.z + a3 * b3.z;
        r.w += a0 * b0.w + a1 * b1.w + a2 * b2.w + a3 * b3.w;
        *(float4*)&orow[c] = r;
    }
}

extern "C" void kernel_launch(void* const* d_in, const int* in_sizes, int n_in,
                              void* d_out, int out_size, void* d_ws, size_t ws_size,
                              hipStream_t stream)
{
    const float* x      = (const float*)d_in[0];
    const float* W_qkv  = (const float*)d_in[1];
    const float* W_proj = (const float*)d_in[2];
    const float* b_proj = (const float*)d_in[3];
    const float* A_qkv  = (const float*)d_in[4];
    const float* B_qkv  = (const float*)d_in[5];
    const float* A_proj = (const float*)d_in[6];
    const float* B_proj = (const float*)d_in[7];
    float* out = (float*)d_out;

    char* ws = (char*)d_ws;
    float* xa    = (float*)(ws);                      // 131072 B
    u16* xhi     = (u16*)(ws + 262144);               // 12582912 B
    u16* xlo     = (u16*)(ws + 12845056);             // 12582912 B
    u16* wqh     = (u16*)(ws + 25427968);             // 3538944 B
    u16* wql     = (u16*)(ws + 28966912);             // 3538944 B
    u16* wph     = (u16*)(ws + 32505856);             // 1179648 B
    u16* wpl     = (u16*)(ws + 33685504);             // 1179648 B
    u16* qkv     = (u16*)(ws + 34865152);             // 37748736 B
    u16* aoh     = (u16*)(ws + 72613888);             // 12582912 B
    u16* aol     = (u16*)(ws + 85196800);             // 12582912 B (end 97779712)

    const int M = 8192;

    split_kernel<<<dim3(3072), dim3(256), 0, stream>>>(x, xhi, xlo, M * 768 / 8);
    transconv_kernel<<<dim3(72, 24), dim3(256), 0, stream>>>(W_qkv, wqh, wql, 768, 2304);
    transconv_kernel<<<dim3(24, 24), dim3(256), 0, stream>>>(W_proj, wph, wpl, 768, 768);
    lora_down_kernel<<<dim3(M), dim3(64), 0, stream>>>(x, A_qkv, xa, 768);
    gemm_split_kernel<true, true, false><<<dim3(1152), dim3(512), 0, stream>>>(
        xhi, xlo, wqh, wql, qkv, M, 2304, 768, xa, B_qkv, nullptr);
    flash_mfma_kernel<<<dim3(768), dim3(256), 0, stream>>>(qkv, aoh, aol);
    gemm_split_kernel<false, false, true><<<dim3(384), dim3(512), 0, stream>>>(
        aoh, aol, wph, wpl, out, M, 768, 768, nullptr, nullptr, b_proj);
    lora_proj_fused_kernel<<<dim3(M), dim3(64), 0, stream>>>(out, A_proj, B_proj);
}

// Round 7
// 188.479 us; speedup vs baseline: 1.4367x; 1.4367x over previous
//
#include <hip/hip_runtime.h>
#include <hip/hip_bf16.h>
#include <math.h>

#define LORA_SCALE 8.0f

typedef _Float16 f16;
typedef __attribute__((ext_vector_type(8))) _Float16 f16x8;
typedef __attribute__((ext_vector_type(4))) float f32x4;
typedef unsigned short u16;
typedef unsigned int u32;

__device__ __forceinline__ u16 f2h(float f) {
    union { f16 h; u16 u; } c;
    c.h = (f16)f;              // v_cvt_f16_f32, RNE
    return c.u;
}
__device__ __forceinline__ u32 pack2h(float lo, float hi) {
    return (u32)f2h(lo) | ((u32)f2h(hi) << 16);
}
__device__ __forceinline__ void g2lds16(const void* g, void* l) {
    __builtin_amdgcn_global_load_lds(
        (const __attribute__((address_space(1))) void*)g,
        (__attribute__((address_space(3))) void*)l, 16, 0, 0);
}

union Frag16 { f16x8 v; u32 u[4]; };

// ---------------- pre-pass: f32 -> f16 (8 elems/thread) ----------------
__global__ __launch_bounds__(256) void cvt_kernel(
    const float* __restrict__ in, u16* __restrict__ out, int n8)
{
    int i = blockIdx.x * 256 + threadIdx.x;
    if (i >= n8) return;
    const float* p = in + (size_t)i * 8;
    float4 a = *(const float4*)p;
    float4 b = *(const float4*)(p + 4);
    uint4 o;
    o.x = pack2h(a.x, a.y); o.y = pack2h(a.z, a.w);
    o.z = pack2h(b.x, b.y); o.w = pack2h(b.z, b.w);
    *(uint4*)&out[(size_t)i * 8] = o;
}

// ---------------- pre-pass: transpose + convert  W[Kd][Nd] f32 -> T[Nd][Kd] f16 -------
__global__ __launch_bounds__(256) void transconv_kernel(
    const float* __restrict__ W, u16* __restrict__ T, int Kd, int Nd)
{
    __shared__ float t[32][36];
    const int r0 = blockIdx.y * 32;
    const int c0 = blockIdx.x * 32;
    const int tid = threadIdx.x;
    {
        int r = tid >> 3, c4 = (tid & 7) * 4;
        float4 v = *(const float4*)&W[(size_t)(r0 + r) * Nd + c0 + c4];
        t[r][c4 + 0] = v.x; t[r][c4 + 1] = v.y; t[r][c4 + 2] = v.z; t[r][c4 + 3] = v.w;
    }
    __syncthreads();
    int oc = tid >> 3;        // original col -> output row (n)
    int oi = tid & 7;         // covers original rows (k) 4*oi..4*oi+3
    u32 w0 = pack2h(t[4 * oi + 0][oc], t[4 * oi + 1][oc]);
    u32 w1 = pack2h(t[4 * oi + 2][oc], t[4 * oi + 3][oc]);
    *(uint2*)&T[(size_t)(c0 + oc) * Kd + r0 + 4 * oi] = make_uint2(w0, w1);
}

// ---------------- K1: lora down-projection  xa[M,4] = X[M,K] @ A[K,4] ----------------
__global__ __launch_bounds__(64) void lora_down_kernel(
    const float* __restrict__ X, const float* __restrict__ A,
    float* __restrict__ out, int K)
{
    const int row = blockIdx.x;
    const int lane = threadIdx.x;
    const float* xr = X + (size_t)row * K;
    float a0 = 0.f, a1 = 0.f, a2 = 0.f, a3 = 0.f;
    for (int c4 = lane * 4; c4 < K; c4 += 256) {
        float4 xv = *(const float4*)&xr[c4];
        const float* ap = &A[(size_t)c4 * 4];
        float4 A0 = *(const float4*)&ap[0];
        float4 A1 = *(const float4*)&ap[4];
        float4 A2 = *(const float4*)&ap[8];
        float4 A3 = *(const float4*)&ap[12];
        a0 = fmaf(xv.x, A0.x, a0); a1 = fmaf(xv.x, A0.y, a1);
        a2 = fmaf(xv.x, A0.z, a2); a3 = fmaf(xv.x, A0.w, a3);
        a0 = fmaf(xv.y, A1.x, a0); a1 = fmaf(xv.y, A1.y, a1);
        a2 = fmaf(xv.y, A1.z, a2); a3 = fmaf(xv.y, A1.w, a3);
        a0 = fmaf(xv.z, A2.x, a0); a1 = fmaf(xv.z, A2.y, a1);
        a2 = fmaf(xv.z, A2.z, a2); a3 = fmaf(xv.z, A2.w, a3);
        a0 = fmaf(xv.w, A3.x, a0); a1 = fmaf(xv.w, A3.y, a1);
        a2 = fmaf(xv.w, A3.z, a2); a3 = fmaf(xv.w, A3.w, a3);
    }
#pragma unroll
    for (int off = 32; off > 0; off >>= 1) {
        a0 += __shfl_down(a0, off);
        a1 += __shfl_down(a1, off);
        a2 += __shfl_down(a2, off);
        a3 += __shfl_down(a3, off);
    }
    if (lane == 0) {
        float4 r; r.x = a0; r.y = a1; r.z = a2; r.w = a3;
        *(float4*)&out[(size_t)row * 4] = r;
    }
}

// ---------------- single-pass fp16 MFMA GEMM, counted-vmcnt ring ----------------------
// C[M,N] = A[M,K] @ B^T[N,K], fp16 in / fp32 acc. 128x128 tile, BK=32, 4 waves (2x2 of
// 64x64). SWAPPED mfma(B,A): lane holds m=lc, n=j*16+lg*4..+3 -> vector stores.
// All 256 threads stage 4x16B/step via global_load_lds (linear LDS dest = tid*16 per
// array-half; chunk-XOR swizzle applied on the GLOBAL source, same XOR on frag reads).
// Ring: stage t0,t1; per step: vmcnt(4) -> barrier -> ds_read -> lgkmcnt(0) -> barrier
// -> stage t+2 into freed buffer -> setprio(1) 16 MFMA setprio(0). XCD-chunked grid.
template<bool OUTH, bool LORA, bool BIAS>
__global__ __launch_bounds__(256, 4) void gemm_f16_kernel(
    const u16* __restrict__ Af, const u16* __restrict__ Bf,
    void* __restrict__ Cout, int M, int N, int K,
    const float* __restrict__ XA, const float* __restrict__ LB,
    const float* __restrict__ bias)
{
    __shared__ __align__(16) u16 Ls[2][2][4096];   // [dbuf][A,B][128*32]
    const int tid = threadIdx.x;
    const int w = tid >> 6, lane = tid & 63;
    const int lc = lane & 15, lg = lane >> 4;
    const int wr = w >> 1, wc = w & 1;             // wave quadrant: 64x64

    const unsigned nbx = (unsigned)N >> 7;
    const unsigned cpx = gridDim.x >> 3;
    const unsigned bid = blockIdx.x;
    const unsigned lid = (bid & 7) * cpx + (bid >> 3);
    const int m0 = (int)(lid / nbx) * 128;
    const int n0 = (int)(lid % nbx) * 128;

    // staging: slot p (0..511 per array) at LDS p*16B; row r=p>>2, chunk c=p&3;
    // source k-chunk inverse-swizzled: c_log = c ^ ((r>>1)&3). Thread t owns slots
    // {t, t+256} of A and B (rows sr and 64+sr; same XOR key since 64>>1=32 ≡ 0 mod 4).
    const int sr = tid >> 2;
    const int scg = ((tid & 3) ^ ((sr >> 1) & 3)) * 8;
    const u16* sA0 = Af + (size_t)(m0 + sr) * K + scg;
    const u16* sA1 = Af + (size_t)(m0 + 64 + sr) * K + scg;
    const u16* sB0 = Bf + (size_t)(n0 + sr) * K + scg;
    const u16* sB1 = Bf + (size_t)(n0 + 64 + sr) * K + scg;

#define STAGE(buf, kt) do { const int _k0 = (kt) << 5;                       \
        g2lds16(sA0 + _k0, (u16*)Ls[buf][0] + tid * 8);                      \
        g2lds16(sA1 + _k0, (u16*)Ls[buf][0] + 2048 + tid * 8);               \
        g2lds16(sB0 + _k0, (u16*)Ls[buf][1] + tid * 8);                      \
        g2lds16(sB1 + _k0, (u16*)Ls[buf][1] + 2048 + tid * 8); } while (0)

    f32x4 acc[4][4];
#pragma unroll
    for (int i = 0; i < 4; ++i)
#pragma unroll
        for (int j = 0; j < 4; ++j) acc[i][j] = (f32x4){0.f, 0.f, 0.f, 0.f};

    const int aswz = (lg ^ ((lc >> 1) & 3)) * 8;
    const int aoff = (wr * 64 + lc) * 32 + aswz;   // + i*512 for m-frag i
    const int boff = (wc * 64 + lc) * 32 + aswz;   // + j*512 for n-frag j

    const int nt = K >> 5;
    STAGE(0, 0);
    STAGE(1, 1);

    for (int t = 0; t < nt; ++t) {
        const int cur = t & 1;
        if (t + 1 < nt) { asm volatile("s_waitcnt vmcnt(4)" ::: "memory"); }
        else            { asm volatile("s_waitcnt vmcnt(0)" ::: "memory"); }
        __builtin_amdgcn_sched_barrier(0);
        __builtin_amdgcn_s_barrier();          // buf[cur] fully staged
        __builtin_amdgcn_sched_barrier(0);

        const u16* cb = &Ls[cur][0][0];
        f16x8 af[4], bfr[4];
#pragma unroll
        for (int i = 0; i < 4; ++i) af[i]  = *(const f16x8*)&cb[aoff + i * 512];
#pragma unroll
        for (int j = 0; j < 4; ++j) bfr[j] = *(const f16x8*)&cb[4096 + boff + j * 512];
        asm volatile("s_waitcnt lgkmcnt(0)" ::: "memory");
        __builtin_amdgcn_sched_barrier(0);
        __builtin_amdgcn_s_barrier();          // all waves done reading buf[cur]
        __builtin_amdgcn_sched_barrier(0);

        if (t + 2 < nt) STAGE(cur, t + 2);     // refill freed buffer; stays in flight
        __builtin_amdgcn_sched_barrier(0);

        __builtin_amdgcn_s_setprio(1);
#pragma unroll
        for (int i = 0; i < 4; ++i)
#pragma unroll
            for (int j = 0; j < 4; ++j)
                acc[i][j] = __builtin_amdgcn_mfma_f32_16x16x32_f16(bfr[j], af[i], acc[i][j], 0, 0, 0);
        __builtin_amdgcn_s_setprio(0);
    }
#undef STAGE

    // epilogue: lane holds rows m0+wr*64+i*16+lc, cols n0+wc*64+j*16+lg*4..+3
    float4 xa4[4];
    if (LORA) {
#pragma unroll
        for (int i = 0; i < 4; ++i)
            xa4[i] = *(const float4*)&XA[(size_t)(m0 + wr * 64 + i * 16 + lc) * 4];
    }
#pragma unroll
    for (int j = 0; j < 4; ++j) {
        const int col = n0 + wc * 64 + j * 16 + lg * 4;
        float4 lb0, lb1, lb2, lb3, bb;
        if (LORA) {
            lb0 = *(const float4*)&LB[0 * N + col];
            lb1 = *(const float4*)&LB[1 * N + col];
            lb2 = *(const float4*)&LB[2 * N + col];
            lb3 = *(const float4*)&LB[3 * N + col];
        }
        if (BIAS) bb = *(const float4*)&bias[col];
#pragma unroll
        for (int i = 0; i < 4; ++i) {
            const int row = m0 + wr * 64 + i * 16 + lc;
            float v0 = acc[i][j][0], v1 = acc[i][j][1], v2 = acc[i][j][2], v3 = acc[i][j][3];
            if (LORA) {
                v0 += LORA_SCALE * (xa4[i].x * lb0.x + xa4[i].y * lb1.x + xa4[i].z * lb2.x + xa4[i].w * lb3.x);
                v1 += LORA_SCALE * (xa4[i].x * lb0.y + xa4[i].y * lb1.y + xa4[i].z * lb2.y + xa4[i].w * lb3.y);
                v2 += LORA_SCALE * (xa4[i].x * lb0.z + xa4[i].y * lb1.z + xa4[i].z * lb2.z + xa4[i].w * lb3.z);
                v3 += LORA_SCALE * (xa4[i].x * lb0.w + xa4[i].y * lb1.w + xa4[i].z * lb2.w + xa4[i].w * lb3.w);
            }
            if (BIAS) { v0 += bb.x; v1 += bb.y; v2 += bb.z; v3 += bb.w; }
            if (OUTH) {
                *(uint2*)&((u16*)Cout)[(size_t)row * N + col] =
                    make_uint2(pack2h(v0, v1), pack2h(v2, v3));
            } else {
                *(float4*)&((float*)Cout)[(size_t)row * N + col] = make_float4(v0, v1, v2, v3);
            }
        }
    }
}

// ---------------- K3: MFMA fp16 flash attention (T14 staging + T13 defer-max) ---------
// qkv rows: [B*N][2304] f16, Q at h*64, K at 768+h*64, V at 1536+h*64. ao out f16.
__global__ __launch_bounds__(256, 3) void flash_mfma_kernel(
    const u16* __restrict__ qkv, u16* __restrict__ ao)
{
    __shared__ __align__(16) u16 Kl[32][72];   // [k][d] f16, 144B rows
    __shared__ __align__(16) u16 Vl[64][40];   // V^T [d][k] f16, 80B rows
    const int fid = blockIdx.x;
    const int bh = fid % 96;
    const int qx = fid / 96;
    const int b = bh / 12, h = bh - b * 12;
    const int tid = threadIdx.x;
    const int w = tid >> 6, lane = tid & 63;
    const int lc = lane & 15, lg = lane >> 4;
    const u16* base = qkv + (size_t)b * 1024 * 2304;
    const int q0 = qx * 128 + w * 32;

    Frag16 qf[2][2];
#pragma unroll
    for (int qi = 0; qi < 2; ++qi)
#pragma unroll
        for (int dc = 0; dc < 2; ++dc)
            qf[qi][dc].v = *(const f16x8*)&base[(size_t)(q0 + qi * 16 + lc) * 2304 + h * 64 + dc * 32 + lg * 8];

    f32x4 o[2][4];
#pragma unroll
    for (int qi = 0; qi < 2; ++qi)
#pragma unroll
        for (int df = 0; df < 4; ++df) o[qi][df] = (f32x4){0.f, 0.f, 0.f, 0.f};
    float mrow[2] = {-1e30f, -1e30f};
    float lrow[2] = {0.f, 0.f};
    const float SC = 0.125f * 1.44269504f;   // d^-0.5 * log2(e)

    const u16* kvbase = base + 768 + h * 64;
    const int skk = tid >> 4, sd0 = (tid & 15) * 4;
    uint2 pk[2], pv[2];
#pragma unroll
    for (int rep = 0; rep < 2; ++rep) {
        const u16* gp = kvbase + (size_t)(skk + rep * 16) * 2304 + sd0;
        pk[rep] = *(const uint2*)gp;
        pv[rep] = *(const uint2*)(gp + 768);
    }

    for (int kv0 = 0; kv0 < 1024; kv0 += 32) {
        __syncthreads();
#pragma unroll
        for (int rep = 0; rep < 2; ++rep) {
            int kk = skk + rep * 16;
            *(uint2*)&Kl[kk][sd0] = pk[rep];
            Vl[sd0 + 0][kk] = (u16)(pv[rep].x & 0xFFFF);
            Vl[sd0 + 1][kk] = (u16)(pv[rep].x >> 16);
            Vl[sd0 + 2][kk] = (u16)(pv[rep].y & 0xFFFF);
            Vl[sd0 + 3][kk] = (u16)(pv[rep].y >> 16);
        }
        if (kv0 + 32 < 1024) {   // T14: issue next-tile loads; hide under MFMA phase
#pragma unroll
            for (int rep = 0; rep < 2; ++rep) {
                const u16* gp = kvbase + (size_t)(kv0 + 32 + skk + rep * 16) * 2304 + sd0;
                pk[rep] = *(const uint2*)gp;
                pv[rep] = *(const uint2*)(gp + 768);
            }
        }
        __syncthreads();

        f16x8 kA[2][2], vA[4];
#pragma unroll
        for (int kf = 0; kf < 2; ++kf)
#pragma unroll
            for (int dc = 0; dc < 2; ++dc)
                kA[kf][dc] = *(const f16x8*)&Kl[kf * 16 + lc][dc * 32 + lg * 8];
#pragma unroll
        for (int df = 0; df < 4; ++df)
            vA[df] = *(const f16x8*)&Vl[df * 16 + lc][lg * 8];

#pragma unroll
        for (int qi = 0; qi < 2; ++qi) {
            f32x4 s0 = {0.f, 0.f, 0.f, 0.f}, s1 = {0.f, 0.f, 0.f, 0.f};
            __builtin_amdgcn_s_setprio(1);
            s0 = __builtin_amdgcn_mfma_f32_16x16x32_f16(kA[0][0], qf[qi][0].v, s0, 0, 0, 0);
            s0 = __builtin_amdgcn_mfma_f32_16x16x32_f16(kA[0][1], qf[qi][1].v, s0, 0, 0, 0);
            s1 = __builtin_amdgcn_mfma_f32_16x16x32_f16(kA[1][0], qf[qi][0].v, s1, 0, 0, 0);
            s1 = __builtin_amdgcn_mfma_f32_16x16x32_f16(kA[1][1], qf[qi][1].v, s1, 0, 0, 0);
            __builtin_amdgcn_s_setprio(0);

            float t0[4], t1[4];
#pragma unroll
            for (int r = 0; r < 4; ++r) { t0[r] = s0[r] * SC; t1[r] = s1[r] * SC; }
            float pm = fmaxf(fmaxf(fmaxf(t0[0], t0[1]), fmaxf(t0[2], t0[3])),
                             fmaxf(fmaxf(t1[0], t1[1]), fmaxf(t1[2], t1[3])));
            pm = fmaxf(pm, __shfl_xor(pm, 16, 64));
            pm = fmaxf(pm, __shfl_xor(pm, 32, 64));
            // T13 defer-max: skip O/l rescale while pm <= m + 8 (P bounded by 2^8)
            if (!__all(pm - mrow[qi] <= 8.0f)) {
                float nm = fmaxf(mrow[qi], pm);
                float corr = exp2f(mrow[qi] - nm);
                mrow[qi] = nm;
                lrow[qi] *= corr;
#pragma unroll
                for (int df = 0; df < 4; ++df) o[qi][df] *= corr;
            }
            const float nmv = mrow[qi];
            float p0[4], p1[4];
            float rs = 0.f;
#pragma unroll
            for (int r = 0; r < 4; ++r) {
                p0[r] = exp2f(t0[r] - nmv); rs += p0[r];
                p1[r] = exp2f(t1[r] - nmv); rs += p1[r];
            }
            rs += __shfl_xor(rs, 16, 64);
            rs += __shfl_xor(rs, 32, 64);
            lrow[qi] += rs;

            u32 w00 = pack2h(p0[0], p0[1]);
            u32 w01 = pack2h(p0[2], p0[3]);
            u32 w10 = pack2h(p1[0], p1[1]);
            u32 w11 = pack2h(p1[2], p1[3]);
            Frag16 pa;
            const int gsel = (lg & 1) * 2;
#pragma unroll
            for (int c = 0; c < 4; ++c) {
                int src = lc | ((gsel + (c >> 1)) << 4);
                u32 a0 = (u32)__shfl((int)((c & 1) ? w01 : w00), src, 64);
                u32 a1 = (u32)__shfl((int)((c & 1) ? w11 : w10), src, 64);
                pa.u[c] = (lg >> 1) ? a1 : a0;
            }
            __builtin_amdgcn_s_setprio(1);
#pragma unroll
            for (int df = 0; df < 4; ++df)
                o[qi][df] = __builtin_amdgcn_mfma_f32_16x16x32_f16(vA[df], pa.v, o[qi][df], 0, 0, 0);
            __builtin_amdgcn_s_setprio(0);
        }
    }

    // epilogue: normalize, store ao f16
#pragma unroll
    for (int qi = 0; qi < 2; ++qi) {
        float inv = 1.f / lrow[qi];
        size_t rowoff = (size_t)(b * 1024 + q0 + qi * 16 + lc) * 768 + h * 64;
#pragma unroll
        for (int df = 0; df < 4; ++df) {
            float v0 = o[qi][df][0] * inv, v1 = o[qi][df][1] * inv;
            float v2 = o[qi][df][2] * inv, v3 = o[qi][df][3] * inv;
            *(uint2*)&ao[rowoff + df * 16 + lg * 4] =
                make_uint2(pack2h(v0, v1), pack2h(v2, v3));
        }
    }
}

// ---------------- K5+K6 fused: out += 8 * (out @ A_proj) @ B_proj, one row/block ------
__global__ __launch_bounds__(64) void lora_proj_fused_kernel(
    float* __restrict__ out, const float* __restrict__ A, const float* __restrict__ Bp)
{
    const int row = blockIdx.x;
    const int lane = threadIdx.x;
    float* orow = out + (size_t)row * 768;
    float4 v[3];
    float a0 = 0.f, a1 = 0.f, a2 = 0.f, a3 = 0.f;
#pragma unroll
    for (int s = 0; s < 3; ++s) {
        const int c = s * 256 + lane * 4;
        v[s] = *(const float4*)&orow[c];
        const float* ap = &A[(size_t)c * 4];
        float4 A0 = *(const float4*)&ap[0];
        float4 A1 = *(const float4*)&ap[4];
        float4 A2 = *(const float4*)&ap[8];
        float4 A3 = *(const float4*)&ap[12];
        a0 = fmaf(v[s].x, A0.x, a0); a1 = fmaf(v[s].x, A0.y, a1);
        a2 = fmaf(v[s].x, A0.z, a2); a3 = fmaf(v[s].x, A0.w, a3);
        a0 = fmaf(v[s].y, A1.x, a0); a1 = fmaf(v[s].y, A1.y, a1);
        a2 = fmaf(v[s].y, A1.z, a2); a3 = fmaf(v[s].y, A1.w, a3);
        a0 = fmaf(v[s].z, A2.x, a0); a1 = fmaf(v[s].z, A2.y, a1);
        a2 = fmaf(v[s].z, A2.z, a2); a3 = fmaf(v[s].z, A2.w, a3);
        a0 = fmaf(v[s].w, A3.x, a0); a1 = fmaf(v[s].w, A3.y, a1);
        a2 = fmaf(v[s].w, A3.z, a2); a3 = fmaf(v[s].w, A3.w, a3);
    }
#pragma unroll
    for (int off = 1; off < 64; off <<= 1) {
        a0 += __shfl_xor(a0, off);
        a1 += __shfl_xor(a1, off);
        a2 += __shfl_xor(a2, off);
        a3 += __shfl_xor(a3, off);
    }
    a0 *= LORA_SCALE; a1 *= LORA_SCALE; a2 *= LORA_SCALE; a3 *= LORA_SCALE;
#pragma unroll
    for (int s = 0; s < 3; ++s) {
        const int c = s * 256 + lane * 4;
        float4 b0 = *(const float4*)&Bp[0 * 768 + c];
        float4 b1 = *(const float4*)&Bp[1 * 768 + c];
        float4 b2 = *(const float4*)&Bp[2 * 768 + c];
        float4 b3 = *(const float4*)&Bp[3 * 768 + c];
        float4 r = v[s];
        r.x += a0 * b0.x + a1 * b1.x + a2 * b2.x + a3 * b3.x;
        r.y += a0 * b0.y + a1 * b1.y + a2 * b2.y + a3 * b3.y;
        r.z += a0 * b0.z + a1 * b1.z + a2 * b2.z + a3 * b3.z;
        r.w += a0 * b0.w + a1 * b1.w + a2 * b2.w + a3 * b3.w;
        *(float4*)&orow[c] = r;
    }
}

extern "C" void kernel_launch(void* const* d_in, const int* in_sizes, int n_in,
                              void* d_out, int out_size, void* d_ws, size_t ws_size,
                              hipStream_t stream)
{
    const float* x      = (const float*)d_in[0];
    const float* W_qkv  = (const float*)d_in[1];
    const float* W_proj = (const float*)d_in[2];
    const float* b_proj = (const float*)d_in[3];
    const float* A_qkv  = (const float*)d_in[4];
    const float* B_qkv  = (const float*)d_in[5];
    const float* A_proj = (const float*)d_in[6];
    const float* B_proj = (const float*)d_in[7];
    float* out = (float*)d_out;

    char* ws = (char*)d_ws;
    float* xa = (float*)(ws);                       // 131072 B
    u16* xh   = (u16*)(ws + 262144);                // 12582912 B  x f16 [8192][768]
    u16* wqh  = (u16*)(ws + 12845056);              // 3538944 B   W_qkv^T f16 [2304][768]
    u16* wph  = (u16*)(ws + 16384000);              // 1179648 B   W_proj^T f16 [768][768]
    u16* qkv  = (u16*)(ws + 17563648);              // 37748736 B  f16 [8192][2304]
    u16* ao   = (u16*)(ws + 55312384);              // 12582912 B  f16 [8192][768]

    const int M = 8192;

    cvt_kernel<<<dim3(3072), dim3(256), 0, stream>>>(x, xh, M * 768 / 8);
    transconv_kernel<<<dim3(72, 24), dim3(256), 0, stream>>>(W_qkv, wqh, 768, 2304);
    transconv_kernel<<<dim3(24, 24), dim3(256), 0, stream>>>(W_proj, wph, 768, 768);
    lora_down_kernel<<<dim3(M), dim3(64), 0, stream>>>(x, A_qkv, xa, 768);
    // qkv(f16) = x @ W_qkv + 8 * xa @ B_qkv
    gemm_f16_kernel<true, true, false><<<dim3(1152), dim3(256), 0, stream>>>(
        xh, wqh, qkv, M, 2304, 768, xa, B_qkv, nullptr);
    flash_mfma_kernel<<<dim3(768), dim3(256), 0, stream>>>(qkv, ao);
    // out = ao @ W_proj + b_proj
    gemm_f16_kernel<false, false, true><<<dim3(384), dim3(256), 0, stream>>>(
        ao, wph, out, M, 768, 768, nullptr, nullptr, b_proj);
    lora_proj_fused_kernel<<<dim3(M), dim3(64), 0, stream>>>(out, A_proj, B_proj);
}